// Round 8
// baseline (387.693 us; speedup 1.0000x reference)
//
#include <hip/hip_runtime.h>
#include <stdint.h>

// ---------------------------------------------------------------------------
// Single-head attention, B=4, S=2048, D=1024, fp32 in/out. bf16 MFMA pipeline.
//
//  0. mega-cvt fp32->bf16 (Wq,Wk,Wv,Wo,query,key in ONE kernel); bias copy
//  1. [q;k] = [qf;kf] @ [Wq;Wk]^T + b    (z=2 batched)
//  2. cvt value -> vf (overlays dead qf)
//  3. vT = Wv @ vf^T + bv                 [1024,8192]
//  4. P  = q @ k^T / 32 (z=4)             [4,2048,2048] (overlays qf/kf/vf)
//  5. softmax rows of P in place
//  6. o  = P @ vT^T (z=4)                 (overlays dead q)
//  7. out= o @ Wo^T + bo -> d_out (fp32)
//
// GEMM engine v5 "B-direct" (T1+T2+T4+T5):
//   Diagnosis: 3 schedules all ~21% MfmaUtil -> shared resource = LDS port
//   (64x64 wave-tile needs 0.5 ds_read_b128 per MFMA; LDS pipe ~12cy/b128 vs
//   MFMA 4.85cy -> LDS ~ MFMA, serialized by barriers). Fix: B operand goes
//   GLOBAL->VGPR directly (per-lane 16B contiguous, L2/L1-resident via T1),
//   prefetched 1 K-tile ahead in named regs (2x unrolled loop, rule #20).
//   A stays in LDS: BM=128 BN=128 BK=32, 4 waves (2Mx2N of 64x64), 3-buffer
//   ring 3x8KB=24KB, global_load_lds + pair-row XOR swizzle (R5-R7 verbatim,
//   0 conflicts). Top-of-iter s_waitcnt vmcnt(6) = exactly A(t)'s drain
//   ([B(t) x4, A(t+1) x2] newer); never drains mid-loop. 1 barrier/K-tile.
//   LDS reads halve to 4/wave/K-tile (ratio 0.25 -> LDS 62% of MFMA pipe).
// ---------------------------------------------------------------------------

typedef __bf16  bf16x8 __attribute__((ext_vector_type(8)));
typedef float   f32x4  __attribute__((ext_vector_type(4)));
typedef unsigned int u32x4 __attribute__((ext_vector_type(4)));

__device__ __forceinline__ unsigned short bf16_rne(float f) {
  unsigned int u = __builtin_bit_cast(unsigned int, f);
  u += 0x7FFFu + ((u >> 16) & 1u);
  return (unsigned short)(u >> 16);
}
__device__ __forceinline__ unsigned int pack2(float a, float b) {
  return (unsigned int)bf16_rne(a) | ((unsigned int)bf16_rne(b) << 16);
}
__device__ __forceinline__ void async16(const unsigned short* g, unsigned short* l) {
  __builtin_amdgcn_global_load_lds(
      (const __attribute__((address_space(1))) unsigned int*)g,
      (__attribute__((address_space(3))) unsigned int*)l,
      16, 0, 0);
}

#define FENCE() asm volatile("" ::: "memory")
#define BAR()   __builtin_amdgcn_s_barrier()

// ---------------------------------------------------------------------------
// C[z][m][n] = scale * sum_k A[z][m][k] * B[z][n][k]  (+ bias)
// M % 128 == 0, N % 128 == 0, K % 64 == 0, K >= 128.
// ---------------------------------------------------------------------------
template<int OUT_F32>
__global__ __launch_bounds__(256, 3) void gemmbd(
    const unsigned short* __restrict__ A, const unsigned short* __restrict__ B,
    void* __restrict__ Cp,
    int K, int lda, int ldb, int ldc,
    long sAz, long sBz, long sCz, long sBiasZ,
    float scale, const float* __restrict__ bias, int bias_mode)
{
  __shared__ unsigned short lds[3 * 4096];    // A-only ring: 3 x 8KB

  // ---- T1: XCD-chunked bijective remap (m204), work linearized x-fastest.
  const int nx   = gridDim.x, ny = gridDim.y;
  const int nwg  = nx * ny * gridDim.z;
  const int orig = (blockIdx.z * ny + blockIdx.y) * nx + blockIdx.x;
  const int xcd  = orig & 7, loc = orig >> 3;
  const int qq   = nwg >> 3, rr = nwg & 7;
  const int w    = (xcd < rr ? xcd * (qq + 1) : rr * (qq + 1) + (xcd - rr) * qq) + loc;
  const int bxi  = w % nx;
  const int byi  = (w / nx) % ny;
  const int bzi  = w / (nx * ny);

  const int tid  = threadIdx.x;
  const int lane = tid & 63;
  const int wid  = tid >> 6;                  // 0..3
  const int bm   = byi * 128;
  const int bn   = bxi * 128;
  const long z   = bzi;

  const unsigned short* Az = A + z * sAz;
  const unsigned short* Bz = B + z * sBz;

  const int wm = wid >> 1;                    // 0..1 (64 rows each)
  const int wn = wid & 1;                     // 0..1 (64 cols each)
  const int al = lane & 15;
  const int ah = lane >> 4;

  // ---- A staging map (pair-row layout + XOR swizzle pre-applied to SOURCE).
  const int t8  = tid >> 3;                   // srow pass0 (0..31)
  const int sul = (tid & 7) ^ (t8 & 7);
  const int dr  = sul >> 2;
  const int kc  = (sul & 3) << 3;
  const unsigned short* Ap0 = Az + (long)(bm + t8 * 2 + dr) * lda + kc;
  const unsigned short* Ap1 = Ap0 + (long)64 * lda;
  const int dA0 = wid * 512, dA1 = wid * 512 + 2048;  // wave-uniform dests

  // ---- A fragment read map (swizzled ds_read, R7 verbatim)
  const int sup     = (((al & 1) << 2) | ah) ^ (al >> 1);
  const int aboff   = wm * 2048 + (al >> 1) * 64 + sup * 8;   // + m*512

  // ---- B direct-from-global per-lane fragment offsets (elements)
  const unsigned short* Bp = Bz + (long)bn * ldb;
  const long bo0 = (long)(wn * 64 +  0 + al) * ldb + ah * 8;
  const long bo1 = (long)(wn * 64 + 16 + al) * ldb + ah * 8;
  const long bo2 = (long)(wn * 64 + 32 + al) * ldb + ah * 8;
  const long bo3 = (long)(wn * 64 + 48 + al) * ldb + ah * 8;

  f32x4 acc[4][4] = {};
  const int nkt = K >> 5;

#define STAGE_A(kt, buf) { const unsigned short* a_ = Ap0 + ((long)(kt) << 5); \
    async16(a_,                    lds + (buf) * 4096 + dA0); \
    async16(Ap1 + ((long)(kt) << 5), lds + (buf) * 4096 + dA1); }

#define LOADB(kt, r0, r1, r2, r3) { const long ko = (long)(kt) << 5; \
    r0 = *(const u32x4*)(Bp + bo0 + ko); \
    r1 = *(const u32x4*)(Bp + bo1 + ko); \
    r2 = *(const u32x4*)(Bp + bo2 + ko); \
    r3 = *(const u32x4*)(Bp + bo3 + ko); }

#define HALF(t, u0, u1, u2, u3, n0, n1, n2, n3) { \
    if ((t) + 1 < nkt) asm volatile("s_waitcnt vmcnt(6)" ::: "memory"); \
    else               asm volatile("s_waitcnt vmcnt(0)" ::: "memory"); \
    BAR(); FENCE(); \
    if ((t) + 1 < nkt) { LOADB((t) + 1, n0, n1, n2, n3); } \
    if ((t) + 2 < nkt) { const int stb = (cur >= 1) ? cur - 1 : cur + 2; STAGE_A((t) + 2, stb); } \
    FENCE(); \
    const unsigned short* ab = lds + cur * 4096 + aboff; \
    bf16x8 a0 = *(const bf16x8*)(ab); \
    bf16x8 a1 = *(const bf16x8*)(ab + 512); \
    bf16x8 a2 = *(const bf16x8*)(ab + 1024); \
    bf16x8 a3 = *(const bf16x8*)(ab + 1536); \
    bf16x8 f0 = __builtin_bit_cast(bf16x8, u0); \
    bf16x8 f1 = __builtin_bit_cast(bf16x8, u1); \
    bf16x8 f2 = __builtin_bit_cast(bf16x8, u2); \
    bf16x8 f3 = __builtin_bit_cast(bf16x8, u3); \
    __builtin_amdgcn_s_setprio(1); \
    acc[0][0] = __builtin_amdgcn_mfma_f32_16x16x32_bf16(a0, f0, acc[0][0], 0, 0, 0); \
    acc[0][1] = __builtin_amdgcn_mfma_f32_16x16x32_bf16(a0, f1, acc[0][1], 0, 0, 0); \
    acc[0][2] = __builtin_amdgcn_mfma_f32_16x16x32_bf16(a0, f2, acc[0][2], 0, 0, 0); \
    acc[0][3] = __builtin_amdgcn_mfma_f32_16x16x32_bf16(a0, f3, acc[0][3], 0, 0, 0); \
    acc[1][0] = __builtin_amdgcn_mfma_f32_16x16x32_bf16(a1, f0, acc[1][0], 0, 0, 0); \
    acc[1][1] = __builtin_amdgcn_mfma_f32_16x16x32_bf16(a1, f1, acc[1][1], 0, 0, 0); \
    acc[1][2] = __builtin_amdgcn_mfma_f32_16x16x32_bf16(a1, f2, acc[1][2], 0, 0, 0); \
    acc[1][3] = __builtin_amdgcn_mfma_f32_16x16x32_bf16(a1, f3, acc[1][3], 0, 0, 0); \
    acc[2][0] = __builtin_amdgcn_mfma_f32_16x16x32_bf16(a2, f0, acc[2][0], 0, 0, 0); \
    acc[2][1] = __builtin_amdgcn_mfma_f32_16x16x32_bf16(a2, f1, acc[2][1], 0, 0, 0); \
    acc[2][2] = __builtin_amdgcn_mfma_f32_16x16x32_bf16(a2, f2, acc[2][2], 0, 0, 0); \
    acc[2][3] = __builtin_amdgcn_mfma_f32_16x16x32_bf16(a2, f3, acc[2][3], 0, 0, 0); \
    acc[3][0] = __builtin_amdgcn_mfma_f32_16x16x32_bf16(a3, f0, acc[3][0], 0, 0, 0); \
    acc[3][1] = __builtin_amdgcn_mfma_f32_16x16x32_bf16(a3, f1, acc[3][1], 0, 0, 0); \
    acc[3][2] = __builtin_amdgcn_mfma_f32_16x16x32_bf16(a3, f2, acc[3][2], 0, 0, 0); \
    acc[3][3] = __builtin_amdgcn_mfma_f32_16x16x32_bf16(a3, f3, acc[3][3], 0, 0, 0); \
    __builtin_amdgcn_s_setprio(0); \
    cur = (cur == 2) ? 0 : cur + 1; }

  // prologue: A tiles 0,1 staged; B tile 0 in regs
  STAGE_A(0, 0); STAGE_A(1, 1);
  u32x4 bA0, bA1, bA2, bA3, bB0, bB1, bB2, bB3;
  LOADB(0, bA0, bA1, bA2, bA3);

  int cur = 0;
  for (int t = 0; t < nkt; t += 2) {
    HALF(t,     bA0, bA1, bA2, bA3, bB0, bB1, bB2, bB3);
    HALF(t + 1, bB0, bB1, bB2, bB3, bA0, bA1, bA2, bA3);
  }

  // Epilogue. C/D layout (m89/m91): col = lane&15, row = (lane>>4)*4 + j
  #pragma unroll
  for (int m = 0; m < 4; ++m) {
    #pragma unroll
    for (int n = 0; n < 4; ++n) {
      #pragma unroll
      for (int j = 0; j < 4; ++j) {
        const int grow = bm + wm * 64 + m * 16 + ah * 4 + j;
        const int gcol = bn + wn * 64 + n * 16 + al;
        float v = acc[m][n][j] * scale;
        if (bias_mode == 1)      v += bias[z * sBiasZ + gcol];
        else if (bias_mode == 2) v += bias[z * sBiasZ + grow];
        const long idx = z * sCz + (long)grow * ldc + gcol;
        if (OUT_F32) ((float*)Cp)[idx] = v;
        else         ((unsigned short*)Cp)[idx] = bf16_rne(v);
      }
    }
  }
}

// ---------------------------------------------------------------------------
// mega-cvt: Wq,Wk,Wv,Wo (512 blocks each) then query (4096), key (4096).
// 10240 blocks total, 8 elems/thread.
// ---------------------------------------------------------------------------
__device__ __forceinline__ void cvt8(const float* in, unsigned short* out, long i) {
  f32x4 a = *(const f32x4*)(in + i * 8);
  f32x4 b = *(const f32x4*)(in + i * 8 + 4);
  u32x4 w;
  w[0] = pack2(a[0], a[1]); w[1] = pack2(a[2], a[3]);
  w[2] = pack2(b[0], b[1]); w[3] = pack2(b[2], b[3]);
  *(u32x4*)(out + i * 8) = w;
}

__global__ __launch_bounds__(256) void mega_cvt(
    const float* __restrict__ wq, const float* __restrict__ wk,
    const float* __restrict__ wv, const float* __restrict__ wo,
    const float* __restrict__ query, const float* __restrict__ key_,
    unsigned short* __restrict__ Wb, unsigned short* __restrict__ qf,
    unsigned short* __restrict__ kf)
{
  const int b = blockIdx.x;
  const long i = (long)(b & 511) * 256 + threadIdx.x;          // within-seg for W
  if (b < 512)        cvt8(wq, Wb,            i);
  else if (b < 1024)  cvt8(wk, Wb + 1048576,  i);
  else if (b < 1536)  cvt8(wv, Wb + 2097152,  i);
  else if (b < 2048)  cvt8(wo, Wb + 3145728,  i);
  else if (b < 6144)  cvt8(query, qf, (long)(b - 2048) * 256 + threadIdx.x);
  else                cvt8(key_,  kf, (long)(b - 6144) * 256 + threadIdx.x);
}

__global__ __launch_bounds__(256) void cvt_f32_bf16(
    const float* __restrict__ in, unsigned short* __restrict__ out, int n8)
{
  const int i = blockIdx.x * 256 + threadIdx.x;
  if (i >= n8) return;
  cvt8(in, out, i);
}

__global__ __launch_bounds__(256) void copy_bias2(
    const float* __restrict__ b0, const float* __restrict__ b1, float* __restrict__ dst)
{
  const int t = blockIdx.x * 256 + threadIdx.x;
  if (t < 1024)       dst[t] = b0[t];
  else if (t < 2048)  dst[t] = b1[t - 1024];
}

// ---------------------------------------------------------------------------
__global__ __launch_bounds__(256) void softmax_inplace(unsigned short* __restrict__ P) {
  const long row = blockIdx.x;
  unsigned short* pr = P + row * 2048;
  const int tid = threadIdx.x;

  u32x4 raw = *(const u32x4*)&pr[tid * 8];
  float s[8];
  #pragma unroll
  for (int i = 0; i < 4; ++i) {
    unsigned int u = raw[i];
    s[2 * i]     = __builtin_bit_cast(float, u << 16);
    s[2 * i + 1] = __builtin_bit_cast(float, u & 0xFFFF0000u);
  }
  float m = s[0];
  #pragma unroll
  for (int i = 1; i < 8; ++i) m = fmaxf(m, s[i]);
  #pragma unroll
  for (int off = 32; off >= 1; off >>= 1) m = fmaxf(m, __shfl_xor(m, off));

  __shared__ float redm[4], reds[4];
  const int wid = tid >> 6, lane = tid & 63;
  if (lane == 0) redm[wid] = m;
  __syncthreads();
  m = fmaxf(fmaxf(redm[0], redm[1]), fmaxf(redm[2], redm[3]));

  float e[8], sum = 0.f;
  #pragma unroll
  for (int i = 0; i < 8; ++i) { e[i] = __expf(s[i] - m); sum += e[i]; }
  #pragma unroll
  for (int off = 32; off >= 1; off >>= 1) sum += __shfl_xor(sum, off);
  if (lane == 0) reds[wid] = sum;
  __syncthreads();
  sum = reds[0] + reds[1] + reds[2] + reds[3];
  const float inv = 1.0f / sum;

  u32x4 outw;
  #pragma unroll
  for (int i = 0; i < 4; ++i) outw[i] = pack2(e[2 * i] * inv, e[2 * i + 1] * inv);
  *(u32x4*)&pr[tid * 8] = outw;
}

// ---------------------------------------------------------------------------
extern "C" void kernel_launch(void* const* d_in, const int* in_sizes, int n_in,
                              void* d_out, int out_size, void* d_ws, size_t ws_size,
                              hipStream_t stream) {
  const float* query = (const float*)d_in[0];
  const float* key_  = (const float*)d_in[1];
  const float* value = (const float*)d_in[2];
  const float* Wq    = (const float*)d_in[3];
  const float* bq    = (const float*)d_in[4];
  const float* Wk    = (const float*)d_in[5];
  const float* bk    = (const float*)d_in[6];
  const float* Wv    = (const float*)d_in[7];
  const float* bv    = (const float*)d_in[8];
  const float* Wo    = (const float*)d_in[9];
  const float* bo    = (const float*)d_in[10];

  unsigned short* ws = (unsigned short*)d_ws;
  unsigned short* qf = ws;                        // [8192][1024] -> vf -> P lower
  unsigned short* kf = ws + 8388608;              // [8192][1024] -> P upper
  unsigned short* vf = ws;                        // overlays dead qf
  unsigned short* P  = ws;                        // [4][2048][2048]
  unsigned short* q  = ws + 16777216;             // [2][8.4M] q,k -> later o
  unsigned short* vT = ws + 33554432;             // [1024][8192]
  unsigned short* Wb = ws + 41943040;             // 4 x [1024][1024] bf16
  float*          bqk= (float*)(ws + 46137344);   // [2][1024] fp32
  unsigned short* o  = q;                         // overlays dead q

  const dim3 blk(256);

  // 0: conversions (2 kernels instead of 7)
  mega_cvt<<<dim3(10240), blk, 0, stream>>>(Wq, Wk, Wv, Wo, query, key_, Wb, qf, kf);
  copy_bias2<<<dim3(8), blk, 0, stream>>>(bq, bk, bqk);

  // 1: [q;k] projections, z=2. M=8192, N=1024, K=1024. 1024 blocks.
  gemmbd<0><<<dim3(8, 64, 2), blk, 0, stream>>>(qf, Wb, q,
      1024, 1024, 1024, 1024, 8388608L, 1048576L, 8388608L, 1024L, 1.0f, bqk, 1);

  // 2: convert value (into region freed by qf)
  cvt_f32_bf16<<<dim3(4096), blk, 0, stream>>>(value, vf, 1048576);

  // 3: vT = Wv @ vf^T + bv. M=1024, N=8192, K=1024, bias per-row. 512 blocks.
  gemmbd<0><<<dim3(64, 8, 1), blk, 0, stream>>>(Wb + 2097152, vf, vT,
      1024, 1024, 1024, 8192, 0L, 0L, 0L, 0L, 1.0f, bv, 2);

  // 4: P = q @ k^T / 32, z=4. M=N=2048, K=1024. 1024 blocks.
  gemmbd<0><<<dim3(16, 16, 4), blk, 0, stream>>>(q, q + 8388608, P,
      1024, 1024, 1024, 2048, 2097152L, 2097152L, 4194304L, 0L, 0.03125f, nullptr, 0);

  // 5: softmax rows in place (8192 rows x 2048)
  softmax_inplace<<<dim3(8192), blk, 0, stream>>>(P);

  // 6: o = P @ vT^T, z=4. M=2048, N=1024, K=2048. 512 blocks.
  gemmbd<0><<<dim3(8, 16, 4), blk, 0, stream>>>(P, vT, o,
      2048, 2048, 8192, 1024, 4194304L, 2048L, 2097152L, 0L, 1.0f, nullptr, 0);

  // 7: out = o @ Wo^T + bo (fp32 out). M=8192, N=1024, K=1024. 512 blocks.
  gemmbd<1><<<dim3(8, 64, 1), blk, 0, stream>>>(o, Wb + 3145728, d_out,
      1024, 1024, 1024, 1024, 0L, 0L, 0L, 0L, 1.0f, bo, 1);
}

// Round 9
// 300.634 us; speedup vs baseline: 1.2896x; 1.2896x over previous
//
#include <hip/hip_runtime.h>
#include <stdint.h>

// ---------------------------------------------------------------------------
// Single-head attention, B=4, S=2048, D=1024, fp32 in/out. bf16 MFMA pipeline.
//
//  0. mega-cvt fp32->bf16 (Wq,Wk,Wv,Wo,query,key); bias copy
//  1. [q;k] = [qf;kf] @ [Wq;Wk]^T + b    (z=2 batched)
//  2. cvt value -> vf (overlays dead qf)
//  3. vT = Wv @ vf^T + bv                 [1024,8192]
//  4. P  = q @ k^T / 32 (z=4)             [4,2048,2048] (overlays qf/kf/vf)
//  5. softmax rows of P in place
//  6. o  = P @ vT^T (z=4)                 (overlays dead q)
//  7. out= o @ Wo^T + bo -> d_out (fp32)
//
// GEMM engine v6 = m97-faithful + T1 (reset after 4 schedule-nulls):
//   BM=128 BN=128 BK=64, 256 thr = 4 waves (2x2 of 64x64).
//   Linear LDS [128][64] x2 = 32KB (bank conflicts ACCEPTED: m97/m98 shows
//   874 TF with 17M conflicts -- at 2-phase the staging path dominates, and
//   linear dest keeps global_load_lds sources fully coalesced, which my
//   pre-swizzled-source variants broke).
//   Staging: 8x global_load_lds dwordx4 per wave; __syncthreads x2 per
//   K-tile; NO inline asm, NO setprio, NO fences -- compiler scheduling
//   (m131-m141: manual pipelining never beats it at this structure).
//   ~90 VGPR + 32KB LDS -> 4-5 resident blocks/CU; cross-block TLP hides
//   the barrier drain (m114).
//   T1: XCD-chunked bijective blockIdx remap (m204), x-fastest (proven
//   R4->R5: FETCH 133->33MB).
// ---------------------------------------------------------------------------

typedef __bf16  bf16x8 __attribute__((ext_vector_type(8)));
typedef float   f32x4  __attribute__((ext_vector_type(4)));
typedef unsigned int u32x4 __attribute__((ext_vector_type(4)));

__device__ __forceinline__ unsigned short bf16_rne(float f) {
  unsigned int u = __builtin_bit_cast(unsigned int, f);
  u += 0x7FFFu + ((u >> 16) & 1u);
  return (unsigned short)(u >> 16);
}
__device__ __forceinline__ unsigned int pack2(float a, float b) {
  return (unsigned int)bf16_rne(a) | ((unsigned int)bf16_rne(b) << 16);
}
__device__ __forceinline__ void async16(const unsigned short* g, unsigned short* l) {
  __builtin_amdgcn_global_load_lds(
      (const __attribute__((address_space(1))) unsigned int*)g,
      (__attribute__((address_space(3))) unsigned int*)l,
      16, 0, 0);
}

// ---------------------------------------------------------------------------
// C[z][m][n] = scale * sum_k A[z][m][k] * B[z][n][k]  (+ bias)
// M % 128 == 0, N % 128 == 0, K % 64 == 0.
// ---------------------------------------------------------------------------
template<int OUT_F32>
__global__ __launch_bounds__(256) void gemm97(
    const unsigned short* __restrict__ A, const unsigned short* __restrict__ B,
    void* __restrict__ Cp,
    int K, int lda, int ldb, int ldc,
    long sAz, long sBz, long sCz, long sBiasZ,
    float scale, const float* __restrict__ bias, int bias_mode)
{
  __shared__ unsigned short As[128 * 64];
  __shared__ unsigned short Bs[128 * 64];

  // ---- T1: XCD-chunked bijective remap (m204), work linearized x-fastest.
  const int nx   = gridDim.x, ny = gridDim.y;
  const int nwg  = nx * ny * gridDim.z;
  const int orig = (blockIdx.z * ny + blockIdx.y) * nx + blockIdx.x;
  const int xcd  = orig & 7, loc = orig >> 3;
  const int qq   = nwg >> 3, rr = nwg & 7;
  const int w    = (xcd < rr ? xcd * (qq + 1) : rr * (qq + 1) + (xcd - rr) * qq) + loc;
  const int bxi  = w % nx;
  const int byi  = (w / nx) % ny;
  const int bzi  = w / (nx * ny);

  const int tid  = threadIdx.x;
  const int lane = tid & 63;
  const int wid  = tid >> 6;
  const int bm   = byi * 128;
  const int bn   = bxi * 128;
  const long z   = bzi;

  const unsigned short* Az = A + z * sAz;
  const unsigned short* Bz = B + z * sBz;

  const int wr = (wid >> 1) * 64;     // wave row offset in tile
  const int wc = (wid & 1)  * 64;     // wave col offset in tile
  const int al = lane & 15;
  const int ah = lane >> 4;

  // staging geometry (m97/R2 verbatim): chunk q = wid*4+i covers rows q*8 +
  // (lane>>3), col (lane&7)*8; LDS linear dest base = q*512 ushorts
  // (+ lane*16B by HW). Fully coalesced: each 8-lane group reads one
  // contiguous 128B row segment.
  const int srow = lane >> 3;          // 0..7
  const int scol = (lane & 7) << 3;    // 0..56

  f32x4 acc[4][4] = {};

  const int nkt = K >> 6;
  for (int kt = 0; kt < nkt; ++kt) {
    const int k0 = kt << 6;
    __syncthreads();                   // protect LDS from previous compute
    #pragma unroll
    for (int i = 0; i < 4; ++i) {
      const int q = wid * 4 + i;
      const int r = q * 8 + srow;
      async16(Az + (long)(bm + r) * lda + (k0 + scol), &As[q * 512]);
      async16(Bz + (long)(bn + r) * ldb + (k0 + scol), &Bs[q * 512]);
    }
    __syncthreads();                   // drains vmcnt(0): tiles ready

    #pragma unroll
    for (int kk = 0; kk < 2; ++kk) {
      bf16x8 af[4], bfr[4];
      #pragma unroll
      for (int m = 0; m < 4; ++m)
        af[m] = *(const bf16x8*)&As[(wr + m * 16 + al) * 64 + kk * 32 + ah * 8];
      #pragma unroll
      for (int n = 0; n < 4; ++n)
        bfr[n] = *(const bf16x8*)&Bs[(wc + n * 16 + al) * 64 + kk * 32 + ah * 8];
      #pragma unroll
      for (int m = 0; m < 4; ++m)
        #pragma unroll
        for (int n = 0; n < 4; ++n)
          acc[m][n] = __builtin_amdgcn_mfma_f32_16x16x32_bf16(af[m], bfr[n], acc[m][n], 0, 0, 0);
    }
  }

  // Epilogue. C/D layout (m89/m91): col = lane&15, row = (lane>>4)*4 + j
  #pragma unroll
  for (int m = 0; m < 4; ++m) {
    #pragma unroll
    for (int n = 0; n < 4; ++n) {
      #pragma unroll
      for (int j = 0; j < 4; ++j) {
        const int grow = bm + wr + m * 16 + ah * 4 + j;
        const int gcol = bn + wc + n * 16 + al;
        float v = acc[m][n][j] * scale;
        if (bias_mode == 1)      v += bias[z * sBiasZ + gcol];
        else if (bias_mode == 2) v += bias[z * sBiasZ + grow];
        const long idx = z * sCz + (long)grow * ldc + gcol;
        if (OUT_F32) ((float*)Cp)[idx] = v;
        else         ((unsigned short*)Cp)[idx] = bf16_rne(v);
      }
    }
  }
}

// ---------------------------------------------------------------------------
__device__ __forceinline__ void cvt8(const float* in, unsigned short* out, long i) {
  f32x4 a = *(const f32x4*)(in + i * 8);
  f32x4 b = *(const f32x4*)(in + i * 8 + 4);
  u32x4 w;
  w[0] = pack2(a[0], a[1]); w[1] = pack2(a[2], a[3]);
  w[2] = pack2(b[0], b[1]); w[3] = pack2(b[2], b[3]);
  *(u32x4*)(out + i * 8) = w;
}

__global__ __launch_bounds__(256) void mega_cvt(
    const float* __restrict__ wq, const float* __restrict__ wk,
    const float* __restrict__ wv, const float* __restrict__ wo,
    const float* __restrict__ query, const float* __restrict__ key_,
    unsigned short* __restrict__ Wb, unsigned short* __restrict__ qf,
    unsigned short* __restrict__ kf)
{
  const int b = blockIdx.x;
  const long i = (long)(b & 511) * 256 + threadIdx.x;          // within-seg for W
  if (b < 512)        cvt8(wq, Wb,            i);
  else if (b < 1024)  cvt8(wk, Wb + 1048576,  i);
  else if (b < 1536)  cvt8(wv, Wb + 2097152,  i);
  else if (b < 2048)  cvt8(wo, Wb + 3145728,  i);
  else if (b < 6144)  cvt8(query, qf, (long)(b - 2048) * 256 + threadIdx.x);
  else                cvt8(key_,  kf, (long)(b - 6144) * 256 + threadIdx.x);
}

__global__ __launch_bounds__(256) void cvt_f32_bf16(
    const float* __restrict__ in, unsigned short* __restrict__ out, int n8)
{
  const int i = blockIdx.x * 256 + threadIdx.x;
  if (i >= n8) return;
  cvt8(in, out, i);
}

__global__ __launch_bounds__(256) void copy_bias2(
    const float* __restrict__ b0, const float* __restrict__ b1, float* __restrict__ dst)
{
  const int t = blockIdx.x * 256 + threadIdx.x;
  if (t < 1024)       dst[t] = b0[t];
  else if (t < 2048)  dst[t] = b1[t - 1024];
}

// ---------------------------------------------------------------------------
__global__ __launch_bounds__(256) void softmax_inplace(unsigned short* __restrict__ P) {
  const long row = blockIdx.x;
  unsigned short* pr = P + row * 2048;
  const int tid = threadIdx.x;

  u32x4 raw = *(const u32x4*)&pr[tid * 8];
  float s[8];
  #pragma unroll
  for (int i = 0; i < 4; ++i) {
    unsigned int u = raw[i];
    s[2 * i]     = __builtin_bit_cast(float, u << 16);
    s[2 * i + 1] = __builtin_bit_cast(float, u & 0xFFFF0000u);
  }
  float m = s[0];
  #pragma unroll
  for (int i = 1; i < 8; ++i) m = fmaxf(m, s[i]);
  #pragma unroll
  for (int off = 32; off >= 1; off >>= 1) m = fmaxf(m, __shfl_xor(m, off));

  __shared__ float redm[4], reds[4];
  const int wid = tid >> 6, lane = tid & 63;
  if (lane == 0) redm[wid] = m;
  __syncthreads();
  m = fmaxf(fmaxf(redm[0], redm[1]), fmaxf(redm[2], redm[3]));

  float e[8], sum = 0.f;
  #pragma unroll
  for (int i = 0; i < 8; ++i) { e[i] = __expf(s[i] - m); sum += e[i]; }
  #pragma unroll
  for (int off = 32; off >= 1; off >>= 1) sum += __shfl_xor(sum, off);
  if (lane == 0) reds[wid] = sum;
  __syncthreads();
  sum = reds[0] + reds[1] + reds[2] + reds[3];
  const float inv = 1.0f / sum;

  u32x4 outw;
  #pragma unroll
  for (int i = 0; i < 4; ++i) outw[i] = pack2(e[2 * i] * inv, e[2 * i + 1] * inv);
  *(u32x4*)&pr[tid * 8] = outw;
}

// ---------------------------------------------------------------------------
extern "C" void kernel_launch(void* const* d_in, const int* in_sizes, int n_in,
                              void* d_out, int out_size, void* d_ws, size_t ws_size,
                              hipStream_t stream) {
  const float* query = (const float*)d_in[0];
  const float* key_  = (const float*)d_in[1];
  const float* value = (const float*)d_in[2];
  const float* Wq    = (const float*)d_in[3];
  const float* bq    = (const float*)d_in[4];
  const float* Wk    = (const float*)d_in[5];
  const float* bk    = (const float*)d_in[6];
  const float* Wv    = (const float*)d_in[7];
  const float* bv    = (const float*)d_in[8];
  const float* Wo    = (const float*)d_in[9];
  const float* bo    = (const float*)d_in[10];

  unsigned short* ws = (unsigned short*)d_ws;
  unsigned short* qf = ws;                        // [8192][1024] -> vf -> P lower
  unsigned short* kf = ws + 8388608;              // [8192][1024] -> P upper
  unsigned short* vf = ws;                        // overlays dead qf
  unsigned short* P  = ws;                        // [4][2048][2048]
  unsigned short* q  = ws + 16777216;             // [2][8.4M] q,k -> later o
  unsigned short* vT = ws + 33554432;             // [1024][8192]
  unsigned short* Wb = ws + 41943040;             // 4 x [1024][1024] bf16
  float*          bqk= (float*)(ws + 46137344);   // [2][1024] fp32
  unsigned short* o  = q;                         // overlays dead q

  const dim3 blk(256);

  // 0: conversions
  mega_cvt<<<dim3(10240), blk, 0, stream>>>(Wq, Wk, Wv, Wo, query, key_, Wb, qf, kf);
  copy_bias2<<<dim3(8), blk, 0, stream>>>(bq, bk, bqk);

  // 1: [q;k] projections, z=2. M=8192, N=1024, K=1024. 1024 blocks.
  gemm97<0><<<dim3(8, 64, 2), blk, 0, stream>>>(qf, Wb, q,
      1024, 1024, 1024, 1024, 8388608L, 1048576L, 8388608L, 1024L, 1.0f, bqk, 1);

  // 2: convert value (into region freed by qf)
  cvt_f32_bf16<<<dim3(4096), blk, 0, stream>>>(value, vf, 1048576);

  // 3: vT = Wv @ vf^T + bv. M=1024, N=8192, K=1024, bias per-row. 512 blocks.
  gemm97<0><<<dim3(64, 8, 1), blk, 0, stream>>>(Wb + 2097152, vf, vT,
      1024, 1024, 1024, 8192, 0L, 0L, 0L, 0L, 1.0f, bv, 2);

  // 4: P = q @ k^T / 32, z=4. M=N=2048, K=1024. 1024 blocks.
  gemm97<0><<<dim3(16, 16, 4), blk, 0, stream>>>(q, q + 8388608, P,
      1024, 1024, 1024, 2048, 2097152L, 2097152L, 4194304L, 0L, 0.03125f, nullptr, 0);

  // 5: softmax rows in place (8192 rows x 2048)
  softmax_inplace<<<dim3(8192), blk, 0, stream>>>(P);

  // 6: o = P @ vT^T, z=4. M=2048, N=1024, K=2048. 512 blocks.
  gemm97<0><<<dim3(8, 16, 4), blk, 0, stream>>>(P, vT, o,
      2048, 2048, 8192, 1024, 4194304L, 2048L, 2097152L, 0L, 1.0f, nullptr, 0);

  // 7: out = o @ Wo^T + bo (fp32 out). M=8192, N=1024, K=1024. 512 blocks.
  gemm97<1><<<dim3(8, 64, 1), blk, 0, stream>>>(o, Wb + 3145728, d_out,
      1024, 1024, 1024, 1024, 0L, 0L, 0L, 0L, 1.0f, bo, 1);
}

// Round 10
// 252.522 us; speedup vs baseline: 1.5353x; 1.1905x over previous
//
#include <hip/hip_runtime.h>
#include <stdint.h>

// ---------------------------------------------------------------------------
// Single-head attention, B=4, S=2048, D=1024, fp32 in/out. bf16 MFMA pipeline.
//
//  0. mega_cvt2: fp32->bf16 Wq,Wk,Wv,Wo,query,key + bias copy (ONE dispatch)
//  1. [q;k] = [qf;kf] @ [Wq;Wk]^T + b    (z=2 batched)
//  2. cvt value -> vf (overlays dead qf; must follow step 1)
//  3. vT = Wv @ vf^T + bv                 [1024,8192]
//  4. P  = q @ k^T / 32 (z=4)             [4,2048,2048] (overlays qf/kf/vf)
//  5. softmax rows of P in place
//  6. o  = P @ vT^T (z=4)                 (overlays dead q)
//  7. out= o @ Wo^T + bo -> d_out (fp32)
//
// GEMM engine = R5's gemm8 VERBATIM (measured best of 5 structures tried:
// R5 63.3us < R7 65 < R4 67.7 < R9 78 < R8 98 on the scores dispatch):
//   BM=256 BN=128 BK=64, 512 thr = 8 waves (4M x 2N), per-wave 64x64.
//   3-buffer LDS ring (144KB), top-of-iter s_waitcnt vmcnt(6), never 0
//   mid-loop. 2 phases per K-tile, 16 MFMA per phase, setprio around MFMA.
//   T2 swizzle via pre-swizzled global SOURCE + swizzled ds_read (0 bank
//   conflicts measured; R9 A/B showed conflicts DO cost time at this shape).
//   T1 XCD-chunked bijective blockIdx remap (FETCH 133->33MB, R4->R5 A/B).
// ---------------------------------------------------------------------------

typedef __bf16  bf16x8 __attribute__((ext_vector_type(8)));
typedef float   f32x4  __attribute__((ext_vector_type(4)));
typedef unsigned int u32x4 __attribute__((ext_vector_type(4)));

__device__ __forceinline__ unsigned short bf16_rne(float f) {
  unsigned int u = __builtin_bit_cast(unsigned int, f);
  u += 0x7FFFu + ((u >> 16) & 1u);
  return (unsigned short)(u >> 16);
}
__device__ __forceinline__ unsigned int pack2(float a, float b) {
  return (unsigned int)bf16_rne(a) | ((unsigned int)bf16_rne(b) << 16);
}
__device__ __forceinline__ void async16(const unsigned short* g, unsigned short* l) {
  __builtin_amdgcn_global_load_lds(
      (const __attribute__((address_space(1))) unsigned int*)g,
      (__attribute__((address_space(3))) unsigned int*)l,
      16, 0, 0);
}

#define FENCE() asm volatile("" ::: "memory")
#define BAR()   __builtin_amdgcn_s_barrier()

// ---------------------------------------------------------------------------
// C[z][m][n] = scale * sum_k A[z][m][k] * B[z][n][k]  (+ bias)
// M % 256 == 0, N % 128 == 0, K % 64 == 0, K >= 192.
// ---------------------------------------------------------------------------
template<int OUT_F32>
__global__ __launch_bounds__(512, 2) void gemm8(
    const unsigned short* __restrict__ A, const unsigned short* __restrict__ B,
    void* __restrict__ Cp,
    int K, int lda, int ldb, int ldc,
    long sAz, long sBz, long sCz, long sBiasZ,
    float scale, const float* __restrict__ bias, int bias_mode)
{
  __shared__ unsigned short lds[3 * 24576];   // per buf: A 16384 + B 8192 ushorts

  // ---- T1: XCD-chunked bijective remap (m204), work linearized x-fastest.
  const int nx   = gridDim.x, ny = gridDim.y;
  const int nwg  = nx * ny * gridDim.z;
  const int orig = (blockIdx.z * ny + blockIdx.y) * nx + blockIdx.x;
  const int xcd  = orig & 7, loc = orig >> 3;
  const int qq   = nwg >> 3, rr = nwg & 7;
  const int w    = (xcd < rr ? xcd * (qq + 1) : rr * (qq + 1) + (xcd - rr) * qq) + loc;
  const int bxi  = w % nx;
  const int byi  = (w / nx) % ny;
  const int bzi  = w / (nx * ny);

  const int tid  = threadIdx.x;
  const int lane = tid & 63;
  const int wid  = tid >> 6;                  // 0..7
  const int bm   = byi * 256;
  const int bn   = bxi * 128;
  const long z   = bzi;

  const unsigned short* Az = A + z * sAz;
  const unsigned short* Bz = B + z * sBz;

  const int wr  = (wid >> 1) * 64;            // wave row in tile (0,64,128,192)
  const int wc  = (wid & 1)  * 64;            // wave col in tile (0,64)
  const int al  = lane & 15;
  const int ah  = lane >> 4;
  const int al7 = lane & 7;

  // staging: per K-tile, per wave: 4 A-loads (8 rows each) + 2 B-loads.
  // global source col pre-swizzled so linear DMA dest yields swizzled LDS.
  const int swz = ((lane & 7) ^ ((lane >> 3) & 7)) << 3;   // ushort offset
  const unsigned short* Apt = Az + (long)(bm + wid * 32 + (lane >> 3)) * lda + swz;
  const unsigned short* Bpt = Bz + (long)(bn + wid * 16 + (lane >> 3)) * ldb + swz;
  const long a8 = (long)lda * 8, b8 = (long)ldb * 8;

  f32x4 acc[4][4] = {};
  const int nkt = K >> 6;

#define STAGE_A(kt, stg) { const unsigned short* a_ = Apt + ((long)(kt) << 6); \
    async16(a_,          (stg) + wid * 2048);        \
    async16(a_ + a8,     (stg) + wid * 2048 + 512);  \
    async16(a_ + 2 * a8, (stg) + wid * 2048 + 1024); \
    async16(a_ + 3 * a8, (stg) + wid * 2048 + 1536); }
#define STAGE_B(kt, stg) { const unsigned short* b_ = Bpt + ((long)(kt) << 6); \
    async16(b_,      (stg) + 16384 + wid * 1024); \
    async16(b_ + b8, (stg) + 16384 + wid * 1024 + 512); }

  // swizzled fragment reads: 16B unit index (kk*4+ah) ^ (row&7), row&7 == al7
#define LDA_(m) { const int r_ = (wr + (m) * 16 + al) * 64; \
    af##m##0 = *(const bf16x8*)&as[r_ + ((ah ^ al7) << 3)]; \
    af##m##1 = *(const bf16x8*)&as[r_ + (((4 | ah) ^ al7) << 3)]; }
#define LDB_(n) { const int r_ = (wc + (n) * 16 + al) * 64; \
    bf##n##0 = *(const bf16x8*)&bs[r_ + ((ah ^ al7) << 3)]; \
    bf##n##1 = *(const bf16x8*)&bs[r_ + (((4 | ah) ^ al7) << 3)]; }
#define MM(m, n) { \
    acc[m][n] = __builtin_amdgcn_mfma_f32_16x16x32_bf16(af##m##0, bf##n##0, acc[m][n], 0, 0, 0); \
    acc[m][n] = __builtin_amdgcn_mfma_f32_16x16x32_bf16(af##m##1, bf##n##1, acc[m][n], 0, 0, 0); }

  // prologue: tiles 0,1 -> bufs 0,1 (12 loads in flight per wave)
  STAGE_A(0, lds); STAGE_B(0, lds);
  STAGE_A(1, lds + 24576); STAGE_B(1, lds + 24576);

  int cur = 0;
  for (int t = 0; t < nkt; ++t) {
    const int stb  = (cur >= 1) ? cur - 1 : cur + 2;   // (t+2)%3
    const bool more = (t + 2) < nkt;

    // tile t resident: wait for all but the newest <=6 loads (tile t+1)
    if (t + 1 < nkt) asm volatile("s_waitcnt vmcnt(6)" ::: "memory");
    else             asm volatile("s_waitcnt vmcnt(0)" ::: "memory");
    BAR(); FENCE();

    const unsigned short* as  = lds + cur * 24576;
    const unsigned short* bs  = as + 16384;
    unsigned short*       stg = lds + stb * 24576;

    bf16x8 af00, af01, af10, af11, af20, af21, af30, af31;
    bf16x8 bf00, bf01, bf10, bf11, bf20, bf21, bf30, bf31;

    // phase 0: A full + B left; stage A(t+2)
    LDA_(0); LDA_(1); LDA_(2); LDA_(3);
    LDB_(0); LDB_(1);
    if (more) STAGE_A(t + 2, stg);
    FENCE(); BAR();
    __builtin_amdgcn_s_setprio(1);
    MM(0,0); MM(1,0); MM(2,0); MM(3,0);
    MM(0,1); MM(1,1); MM(2,1); MM(3,1);
    __builtin_amdgcn_s_setprio(0);
    BAR(); FENCE();

    // phase 1: B right; stage B(t+2)
    LDB_(2); LDB_(3);
    if (more) STAGE_B(t + 2, stg);
    FENCE(); BAR();
    __builtin_amdgcn_s_setprio(1);
    MM(0,2); MM(1,2); MM(2,2); MM(3,2);
    MM(0,3); MM(1,3); MM(2,3); MM(3,3);
    __builtin_amdgcn_s_setprio(0);
    BAR(); FENCE();

    cur = (cur == 2) ? 0 : cur + 1;
  }

  // Epilogue. C/D layout (m89/m91): col = lane&15, row = (lane>>4)*4 + j
  #pragma unroll
  for (int m = 0; m < 4; ++m) {
    #pragma unroll
    for (int n = 0; n < 4; ++n) {
      #pragma unroll
      for (int j = 0; j < 4; ++j) {
        const int grow = bm + wr + m * 16 + ah * 4 + j;
        const int gcol = bn + wc + n * 16 + al;
        float v = acc[m][n][j] * scale;
        if (bias_mode == 1)      v += bias[z * sBiasZ + gcol];
        else if (bias_mode == 2) v += bias[z * sBiasZ + grow];
        const long idx = z * sCz + (long)grow * ldc + gcol;
        if (OUT_F32) ((float*)Cp)[idx] = v;
        else         ((unsigned short*)Cp)[idx] = bf16_rne(v);
      }
    }
  }
}

// ---------------------------------------------------------------------------
__device__ __forceinline__ void cvt8(const float* in, unsigned short* out, long i) {
  f32x4 a = *(const f32x4*)(in + i * 8);
  f32x4 b = *(const f32x4*)(in + i * 8 + 4);
  u32x4 w;
  w[0] = pack2(a[0], a[1]); w[1] = pack2(a[2], a[3]);
  w[2] = pack2(b[0], b[1]); w[3] = pack2(b[2], b[3]);
  *(u32x4*)(out + i * 8) = w;
}

// mega_cvt2: Wq,Wk,Wv,Wo (512 blocks each), query (4096), key (4096),
// bias copy (8 blocks). 10248 blocks total.
__global__ __launch_bounds__(256) void mega_cvt2(
    const float* __restrict__ wq, const float* __restrict__ wk,
    const float* __restrict__ wv, const float* __restrict__ wo,
    const float* __restrict__ query, const float* __restrict__ key_,
    const float* __restrict__ bq, const float* __restrict__ bk,
    unsigned short* __restrict__ Wb, unsigned short* __restrict__ qf,
    unsigned short* __restrict__ kf, float* __restrict__ bqk)
{
  const int b = blockIdx.x;
  if (b < 2048) {
    const long i = (long)(b & 511) * 256 + threadIdx.x;
    if (b < 512)        cvt8(wq, Wb,            i);
    else if (b < 1024)  cvt8(wk, Wb + 1048576,  i);
    else if (b < 1536)  cvt8(wv, Wb + 2097152,  i);
    else                cvt8(wo, Wb + 3145728,  i);
  } else if (b < 6144) {
    cvt8(query, qf, (long)(b - 2048) * 256 + threadIdx.x);
  } else if (b < 10240) {
    cvt8(key_,  kf, (long)(b - 6144) * 256 + threadIdx.x);
  } else {
    const int t = (b - 10240) * 256 + threadIdx.x;   // 0..2047
    if (t < 1024) bqk[t] = bq[t];
    else          bqk[t] = bk[t - 1024];
  }
}

__global__ __launch_bounds__(256) void cvt_f32_bf16(
    const float* __restrict__ in, unsigned short* __restrict__ out, int n8)
{
  const int i = blockIdx.x * 256 + threadIdx.x;
  if (i >= n8) return;
  cvt8(in, out, i);
}

// ---------------------------------------------------------------------------
__global__ __launch_bounds__(256) void softmax_inplace(unsigned short* __restrict__ P) {
  const long row = blockIdx.x;
  unsigned short* pr = P + row * 2048;
  const int tid = threadIdx.x;

  u32x4 raw = *(const u32x4*)&pr[tid * 8];
  float s[8];
  #pragma unroll
  for (int i = 0; i < 4; ++i) {
    unsigned int u = raw[i];
    s[2 * i]     = __builtin_bit_cast(float, u << 16);
    s[2 * i + 1] = __builtin_bit_cast(float, u & 0xFFFF0000u);
  }
  float m = s[0];
  #pragma unroll
  for (int i = 1; i < 8; ++i) m = fmaxf(m, s[i]);
  #pragma unroll
  for (int off = 32; off >= 1; off >>= 1) m = fmaxf(m, __shfl_xor(m, off));

  __shared__ float redm[4], reds[4];
  const int wid = tid >> 6, lane = tid & 63;
  if (lane == 0) redm[wid] = m;
  __syncthreads();
  m = fmaxf(fmaxf(redm[0], redm[1]), fmaxf(redm[2], redm[3]));

  float e[8], sum = 0.f;
  #pragma unroll
  for (int i = 0; i < 8; ++i) { e[i] = __expf(s[i] - m); sum += e[i]; }
  #pragma unroll
  for (int off = 32; off >= 1; off >>= 1) sum += __shfl_xor(sum, off);
  if (lane == 0) reds[wid] = sum;
  __syncthreads();
  sum = reds[0] + reds[1] + reds[2] + reds[3];
  const float inv = 1.0f / sum;

  u32x4 outw;
  #pragma unroll
  for (int i = 0; i < 4; ++i) outw[i] = pack2(e[2 * i] * inv, e[2 * i + 1] * inv);
  *(u32x4*)&pr[tid * 8] = outw;
}

// ---------------------------------------------------------------------------
extern "C" void kernel_launch(void* const* d_in, const int* in_sizes, int n_in,
                              void* d_out, int out_size, void* d_ws, size_t ws_size,
                              hipStream_t stream) {
  const float* query = (const float*)d_in[0];
  const float* key_  = (const float*)d_in[1];
  const float* value = (const float*)d_in[2];
  const float* Wq    = (const float*)d_in[3];
  const float* bq    = (const float*)d_in[4];
  const float* Wk    = (const float*)d_in[5];
  const float* bk    = (const float*)d_in[6];
  const float* Wv    = (const float*)d_in[7];
  const float* bv    = (const float*)d_in[8];
  const float* Wo    = (const float*)d_in[9];
  const float* bo    = (const float*)d_in[10];

  unsigned short* ws = (unsigned short*)d_ws;
  unsigned short* qf = ws;                        // [8192][1024] -> vf -> P lower
  unsigned short* kf = ws + 8388608;              // [8192][1024] -> P upper
  unsigned short* vf = ws;                        // overlays dead qf
  unsigned short* P  = ws;                        // [4][2048][2048]
  unsigned short* q  = ws + 16777216;             // [2][8.4M] q,k -> later o
  unsigned short* vT = ws + 33554432;             // [1024][8192]
  unsigned short* Wb = ws + 41943040;             // 4 x [1024][1024] bf16
  float*          bqk= (float*)(ws + 46137344);   // [2][1024] fp32
  unsigned short* o  = q;                         // overlays dead q

  const dim3 blk(256), blk8(512);

  // 0: all prologue conversions + bias copy in ONE dispatch
  mega_cvt2<<<dim3(10248), blk, 0, stream>>>(Wq, Wk, Wv, Wo, query, key_,
                                             bq, bk, Wb, qf, kf, bqk);

  // 1: [q;k] projections, z=2. M=8192, N=1024, K=1024. 512 blocks.
  gemm8<0><<<dim3(8, 32, 2), blk8, 0, stream>>>(qf, Wb, q,
      1024, 1024, 1024, 1024, 8388608L, 1048576L, 8388608L, 1024L, 1.0f, bqk, 1);

  // 2: convert value (into region freed by qf)
  cvt_f32_bf16<<<dim3(4096), blk, 0, stream>>>(value, vf, 1048576);

  // 3: vT = Wv @ vf^T + bv. M=1024, N=8192, K=1024, bias per-row. 256 blocks.
  gemm8<0><<<dim3(64, 4, 1), blk8, 0, stream>>>(Wb + 2097152, vf, vT,
      1024, 1024, 1024, 8192, 0L, 0L, 0L, 0L, 1.0f, bv, 2);

  // 4: P = q @ k^T / 32, z=4. M=N=2048, K=1024. 512 blocks.
  gemm8<0><<<dim3(16, 8, 4), blk8, 0, stream>>>(q, q + 8388608, P,
      1024, 1024, 1024, 2048, 2097152L, 2097152L, 4194304L, 0L, 0.03125f, nullptr, 0);

  // 5: softmax rows in place (8192 rows x 2048)
  softmax_inplace<<<dim3(8192), blk, 0, stream>>>(P);

  // 6: o = P @ vT^T, z=4. M=2048, N=1024, K=2048. 256 blocks.
  gemm8<0><<<dim3(8, 8, 4), blk8, 0, stream>>>(P, vT, o,
      2048, 2048, 8192, 1024, 4194304L, 2048L, 2097152L, 0L, 1.0f, nullptr, 0);

  // 7: out = o @ Wo^T + bo (fp32 out). M=8192, N=1024, K=1024. 256 blocks.
  gemm8<1><<<dim3(8, 32, 1), blk8, 0, stream>>>(o, Wb + 3145728, d_out,
      1024, 1024, 1024, 1024, 0L, 0L, 0L, 0L, 1.0f, bo, 1);
}

// Round 11
// 235.036 us; speedup vs baseline: 1.6495x; 1.0744x over previous
//
#include <hip/hip_runtime.h>
#include <stdint.h>

// ---------------------------------------------------------------------------
// Single-head attention, B=4, S=2048, D=1024, fp32 in/out. bf16 MFMA pipeline.
//
//  0. mega_cvt2: fp32->bf16 Wq,Wk,Wv,Wo,query,key + bias copy (ONE dispatch)
//  1. [q;k] = [qf;kf] @ [Wq;Wk]^T + b    (z=2 batched)      [gemm256]
//  2. cvt value -> vf (overlays dead qf)
//  3. vT = Wv @ vf^T + bv                 [1024,8192]        [gemm8]
//  4. P  = q @ k^T / 32 (z=4)             [4,2048,2048]      [gemm256]
//  5. softmax rows of P in place
//  6. o  = P @ vT^T (z=4)                                    [gemm8]
//  7. out= o @ Wo^T + bo -> d_out (fp32)                     [gemm8]
//
// gemm256 = m201-faithful 8-phase 256x256 engine (new this round):
//   BM=BN=256 BK=64, 512 thr = 8 waves (2M x 4N), wave-tile 128x64,
//   0.375 ds_read_b128 per MFMA. 2-dbuf LDS 128KB. Per K-tile 4 phase-pairs:
//     ph0: read A m0-3 kk01 (8) + B n01 (4) | stage A01 | BAR | 16 MFMA | BAR
//     ph1: read B n23 (4)                   | stage A23 | BAR | 16 MFMA | BAR
//     ph2: read A m4-7 (8, regs recycled)   | stage B01 | BAR | 16 MFMA | BAR
//     ph3: (no reads)                       | stage B23 | BAR | 16 MFMA
//   Next-tile stages front-loaded across phases -> top-of-tile vmcnt(0)
//   drain is ~free (last pair issued ~1 phase earlier). setprio on clusters
//   (T5: +21-25% on 8-phase, m218b). T1 XCD remap + proven R5 swizzle
//   (pre-swizzled source, 0 conflicts). Bit-identical numerics vs R10.
// gemm8 = R5/R10 engine verbatim (measured best for the N=1024-ish shapes).
// ---------------------------------------------------------------------------

typedef __bf16  bf16x8 __attribute__((ext_vector_type(8)));
typedef float   f32x4  __attribute__((ext_vector_type(4)));
typedef unsigned int u32x4 __attribute__((ext_vector_type(4)));

__device__ __forceinline__ unsigned short bf16_rne(float f) {
  unsigned int u = __builtin_bit_cast(unsigned int, f);
  u += 0x7FFFu + ((u >> 16) & 1u);
  return (unsigned short)(u >> 16);
}
__device__ __forceinline__ unsigned int pack2(float a, float b) {
  return (unsigned int)bf16_rne(a) | ((unsigned int)bf16_rne(b) << 16);
}
__device__ __forceinline__ void async16(const unsigned short* g, unsigned short* l) {
  __builtin_amdgcn_global_load_lds(
      (const __attribute__((address_space(1))) unsigned int*)g,
      (__attribute__((address_space(3))) unsigned int*)l,
      16, 0, 0);
}

#define FENCE() asm volatile("" ::: "memory")
#define BAR()   __builtin_amdgcn_s_barrier()

#define MFMA_ __builtin_amdgcn_mfma_f32_16x16x32_bf16

// T1: XCD-chunked bijective remap (m204), work linearized x-fastest.
#define T1_REMAP() \
  const int nx   = gridDim.x, ny = gridDim.y; \
  const int nwg  = nx * ny * gridDim.z; \
  const int orig = (blockIdx.z * ny + blockIdx.y) * nx + blockIdx.x; \
  const int xcd  = orig & 7, loc = orig >> 3; \
  const int qq   = nwg >> 3, rr = nwg & 7; \
  const int w    = (xcd < rr ? xcd * (qq + 1) : rr * (qq + 1) + (xcd - rr) * qq) + loc; \
  const int bxi  = w % nx; \
  const int byi  = (w / nx) % ny; \
  const int bzi  = w / (nx * ny);

// ---------------------------------------------------------------------------
// gemm256: C[z][m][n] = scale * sum_k A[z][m][k]*B[z][n][k] (+bias)
// M % 256 == 0, N % 256 == 0, K % 64 == 0, K >= 128.
// ---------------------------------------------------------------------------
template<int OUT_F32>
__global__ __launch_bounds__(512, 1) void gemm256(
    const unsigned short* __restrict__ A, const unsigned short* __restrict__ B,
    void* __restrict__ Cp,
    int K, int lda, int ldb, int ldc,
    long sAz, long sBz, long sCz, long sBiasZ,
    float scale, const float* __restrict__ bias, int bias_mode)
{
  __shared__ unsigned short lds[2 * 32768];   // dbuf: A 16384 + B 16384 ushorts

  T1_REMAP();

  const int tid  = threadIdx.x;
  const int lane = tid & 63;
  const int wid  = tid >> 6;                  // 0..7
  const int bm   = byi * 256;
  const int bn   = bxi * 256;
  const long z   = bzi;

  const unsigned short* Az = A + z * sAz;
  const unsigned short* Bz = B + z * sBz;

  const int wm  = wid >> 2;                   // 0..1  (128 rows)
  const int wn  = wid & 3;                    // 0..3  (64 cols)
  const int al  = lane & 15;
  const int ah  = lane >> 4;
  const int al7 = lane & 7;

  // staging (R5 formulas): per wave 4 A-loads + 4 B-loads per K-tile,
  // each load = 8 rows x 128B, source col pre-swizzled (involution),
  // LDS dest linear row-major [256][64].
  const int swz = ((lane & 7) ^ ((lane >> 3) & 7)) << 3;
  const unsigned short* Apt = Az + (long)(bm + wid * 32 + (lane >> 3)) * lda + swz;
  const unsigned short* Bpt = Bz + (long)(bn + wid * 32 + (lane >> 3)) * ldb + swz;
  const long a8 = (long)lda * 8, b8 = (long)ldb * 8;

#define SA01(kt, stg) { const unsigned short* p_ = Apt + ((long)(kt) << 6); \
    async16(p_,      (stg) + wid * 2048);       \
    async16(p_ + a8, (stg) + wid * 2048 + 512); }
#define SA23(kt, stg) { const unsigned short* p_ = Apt + ((long)(kt) << 6) + 2 * a8; \
    async16(p_,      (stg) + wid * 2048 + 1024); \
    async16(p_ + a8, (stg) + wid * 2048 + 1536); }
#define SB01(kt, stg) { const unsigned short* p_ = Bpt + ((long)(kt) << 6); \
    async16(p_,      (stg) + 16384 + wid * 2048);       \
    async16(p_ + b8, (stg) + 16384 + wid * 2048 + 512); }
#define SB23(kt, stg) { const unsigned short* p_ = Bpt + ((long)(kt) << 6) + 2 * b8; \
    async16(p_,      (stg) + 16384 + wid * 2048 + 1024); \
    async16(p_ + b8, (stg) + 16384 + wid * 2048 + 1536); }

  // swizzled fragment reads: physical 16B unit = logical(kk*4+ah) ^ (row&7),
  // row&7 == al7 for 16-aligned bases.
#define LDA2(v0, v1, mm) { const int r_ = (wm * 128 + (mm) * 16 + al) * 64; \
    v0 = *(const bf16x8*)&as[r_ + ((ah ^ al7) << 3)]; \
    v1 = *(const bf16x8*)&as[r_ + (((4 | ah) ^ al7) << 3)]; }
#define LDB2(v0, v1, nn) { const int r_ = (wn * 64 + (nn) * 16 + al) * 64; \
    v0 = *(const bf16x8*)&bs[r_ + ((ah ^ al7) << 3)]; \
    v1 = *(const bf16x8*)&bs[r_ + (((4 | ah) ^ al7) << 3)]; }
#define MM2(mi, ni, av0, av1, bv0, bv1) { \
    acc[mi][ni] = MFMA_(av0, bv0, acc[mi][ni], 0, 0, 0); \
    acc[mi][ni] = MFMA_(av1, bv1, acc[mi][ni], 0, 0, 0); }

  f32x4 acc[8][4] = {};
  const int nkt = K >> 6;

  // prologue: tile 0 into dbuf 0 (8 loads/wave in flight)
  SA01(0, lds); SA23(0, lds); SB01(0, lds); SB23(0, lds);

  int cur = 0;
  for (int t = 0; t < nkt; ++t) {
    // tile t resident (its 8 loads were front-loaded during t-1's phases)
    asm volatile("s_waitcnt vmcnt(0)" ::: "memory");
    BAR(); FENCE();

    const unsigned short* as  = lds + cur * 32768;
    const unsigned short* bs  = as + 16384;
    unsigned short*       stg = lds + (cur ^ 1) * 32768;
    const bool more = (t + 1) < nkt;

    bf16x8 a0k0, a0k1, a1k0, a1k1, a2k0, a2k1, a3k0, a3k1;
    bf16x8 b0k0, b0k1, b1k0, b1k1, b2k0, b2k1, b3k0, b3k1;

    // ---- ph0: A m0-3 (8 reads) + B n01 (4); stage A01(t+1)
    LDA2(a0k0, a0k1, 0); LDA2(a1k0, a1k1, 1); LDA2(a2k0, a2k1, 2); LDA2(a3k0, a3k1, 3);
    LDB2(b0k0, b0k1, 0); LDB2(b1k0, b1k1, 1);
    if (more) SA01(t + 1, stg);
    FENCE(); BAR();
    __builtin_amdgcn_s_setprio(1);
    MM2(0,0, a0k0,a0k1, b0k0,b0k1); MM2(1,0, a1k0,a1k1, b0k0,b0k1);
    MM2(2,0, a2k0,a2k1, b0k0,b0k1); MM2(3,0, a3k0,a3k1, b0k0,b0k1);
    MM2(0,1, a0k0,a0k1, b1k0,b1k1); MM2(1,1, a1k0,a1k1, b1k0,b1k1);
    MM2(2,1, a2k0,a2k1, b1k0,b1k1); MM2(3,1, a3k0,a3k1, b1k0,b1k1);
    __builtin_amdgcn_s_setprio(0);
    BAR(); FENCE();

    // ---- ph1: B n23 (4 reads); stage A23(t+1)
    LDB2(b2k0, b2k1, 2); LDB2(b3k0, b3k1, 3);
    if (more) SA23(t + 1, stg);
    FENCE(); BAR();
    __builtin_amdgcn_s_setprio(1);
    MM2(0,2, a0k0,a0k1, b2k0,b2k1); MM2(1,2, a1k0,a1k1, b2k0,b2k1);
    MM2(2,2, a2k0,a2k1, b2k0,b2k1); MM2(3,2, a3k0,a3k1, b2k0,b2k1);
    MM2(0,3, a0k0,a0k1, b3k0,b3k1); MM2(1,3, a1k0,a1k1, b3k0,b3k1);
    MM2(2,3, a2k0,a2k1, b3k0,b3k1); MM2(3,3, a3k0,a3k1, b3k0,b3k1);
    __builtin_amdgcn_s_setprio(0);
    BAR(); FENCE();

    // ---- ph2: A m4-7 (8 reads, recycle registers); stage B01(t+1)
    LDA2(a0k0, a0k1, 4); LDA2(a1k0, a1k1, 5); LDA2(a2k0, a2k1, 6); LDA2(a3k0, a3k1, 7);
    if (more) SB01(t + 1, stg);
    FENCE(); BAR();
    __builtin_amdgcn_s_setprio(1);
    MM2(4,0, a0k0,a0k1, b0k0,b0k1); MM2(5,0, a1k0,a1k1, b0k0,b0k1);
    MM2(6,0, a2k0,a2k1, b0k0,b0k1); MM2(7,0, a3k0,a3k1, b0k0,b0k1);
    MM2(4,1, a0k0,a0k1, b1k0,b1k1); MM2(5,1, a1k0,a1k1, b1k0,b1k1);
    MM2(6,1, a2k0,a2k1, b1k0,b1k1); MM2(7,1, a3k0,a3k1, b1k0,b1k1);
    __builtin_amdgcn_s_setprio(0);
    BAR(); FENCE();

    // ---- ph3: no reads; stage B23(t+1)
    if (more) SB23(t + 1, stg);
    FENCE(); BAR();
    __builtin_amdgcn_s_setprio(1);
    MM2(4,2, a0k0,a0k1, b2k0,b2k1); MM2(5,2, a1k0,a1k1, b2k0,b2k1);
    MM2(6,2, a2k0,a2k1, b2k0,b2k1); MM2(7,2, a3k0,a3k1, b2k0,b2k1);
    MM2(4,3, a0k0,a0k1, b3k0,b3k1); MM2(5,3, a1k0,a1k1, b3k0,b3k1);
    MM2(6,3, a2k0,a2k1, b3k0,b3k1); MM2(7,3, a3k0,a3k1, b3k0,b3k1);
    __builtin_amdgcn_s_setprio(0);

    cur ^= 1;
  }

  // Epilogue (R6-verified). C/D layout: col = lane&15, row = (lane>>4)*4 + j
  #pragma unroll
  for (int m = 0; m < 8; ++m) {
    #pragma unroll
    for (int n = 0; n < 4; ++n) {
      #pragma unroll
      for (int j = 0; j < 4; ++j) {
        const int grow = bm + wm * 128 + m * 16 + ah * 4 + j;
        const int gcol = bn + wn * 64 + n * 16 + al;
        float v = acc[m][n][j] * scale;
        if (bias_mode == 1)      v += bias[z * sBiasZ + gcol];
        else if (bias_mode == 2) v += bias[z * sBiasZ + grow];
        const long idx = z * sCz + (long)grow * ldc + gcol;
        if (OUT_F32) ((float*)Cp)[idx] = v;
        else         ((unsigned short*)Cp)[idx] = bf16_rne(v);
      }
    }
  }
}

// ---------------------------------------------------------------------------
// gemm8 = R10 verbatim. M % 256 == 0, N % 128 == 0, K % 64 == 0, K >= 192.
// ---------------------------------------------------------------------------
template<int OUT_F32>
__global__ __launch_bounds__(512, 2) void gemm8(
    const unsigned short* __restrict__ A, const unsigned short* __restrict__ B,
    void* __restrict__ Cp,
    int K, int lda, int ldb, int ldc,
    long sAz, long sBz, long sCz, long sBiasZ,
    float scale, const float* __restrict__ bias, int bias_mode)
{
  __shared__ unsigned short lds[3 * 24576];   // per buf: A 16384 + B 8192 ushorts

  T1_REMAP();

  const int tid  = threadIdx.x;
  const int lane = tid & 63;
  const int wid  = tid >> 6;                  // 0..7
  const int bm   = byi * 256;
  const int bn   = bxi * 128;
  const long z   = bzi;

  const unsigned short* Az = A + z * sAz;
  const unsigned short* Bz = B + z * sBz;

  const int wr  = (wid >> 1) * 64;
  const int wc  = (wid & 1)  * 64;
  const int al  = lane & 15;
  const int ah  = lane >> 4;
  const int al7 = lane & 7;

  const int swz = ((lane & 7) ^ ((lane >> 3) & 7)) << 3;
  const unsigned short* Apt = Az + (long)(bm + wid * 32 + (lane >> 3)) * lda + swz;
  const unsigned short* Bpt = Bz + (long)(bn + wid * 16 + (lane >> 3)) * ldb + swz;
  const long a8 = (long)lda * 8, b8 = (long)ldb * 8;

  f32x4 acc[4][4] = {};
  const int nkt = K >> 6;

#define STAGE_A(kt, stg) { const unsigned short* a_ = Apt + ((long)(kt) << 6); \
    async16(a_,          (stg) + wid * 2048);        \
    async16(a_ + a8,     (stg) + wid * 2048 + 512);  \
    async16(a_ + 2 * a8, (stg) + wid * 2048 + 1024); \
    async16(a_ + 3 * a8, (stg) + wid * 2048 + 1536); }
#define STAGE_B(kt, stg) { const unsigned short* b_ = Bpt + ((long)(kt) << 6); \
    async16(b_,      (stg) + 16384 + wid * 1024); \
    async16(b_ + b8, (stg) + 16384 + wid * 1024 + 512); }

#define LDA_(m) { const int r_ = (wr + (m) * 16 + al) * 64; \
    af##m##0 = *(const bf16x8*)&as[r_ + ((ah ^ al7) << 3)]; \
    af##m##1 = *(const bf16x8*)&as[r_ + (((4 | ah) ^ al7) << 3)]; }
#define LDB_(n) { const int r_ = (wc + (n) * 16 + al) * 64; \
    bf##n##0 = *(const bf16x8*)&bs[r_ + ((ah ^ al7) << 3)]; \
    bf##n##1 = *(const bf16x8*)&bs[r_ + (((4 | ah) ^ al7) << 3)]; }
#define MM(m, n) { \
    acc[m][n] = MFMA_(af##m##0, bf##n##0, acc[m][n], 0, 0, 0); \
    acc[m][n] = MFMA_(af##m##1, bf##n##1, acc[m][n], 0, 0, 0); }

  STAGE_A(0, lds); STAGE_B(0, lds);
  STAGE_A(1, lds + 24576); STAGE_B(1, lds + 24576);

  int cur = 0;
  for (int t = 0; t < nkt; ++t) {
    const int stb  = (cur >= 1) ? cur - 1 : cur + 2;
    const bool more = (t + 2) < nkt;

    if (t + 1 < nkt) asm volatile("s_waitcnt vmcnt(6)" ::: "memory");
    else             asm volatile("s_waitcnt vmcnt(0)" ::: "memory");
    BAR(); FENCE();

    const unsigned short* as  = lds + cur * 24576;
    const unsigned short* bs  = as + 16384;
    unsigned short*       stg = lds + stb * 24576;

    bf16x8 af00, af01, af10, af11, af20, af21, af30, af31;
    bf16x8 bf00, bf01, bf10, bf11, bf20, bf21, bf30, bf31;

    LDA_(0); LDA_(1); LDA_(2); LDA_(3);
    LDB_(0); LDB_(1);
    if (more) STAGE_A(t + 2, stg);
    FENCE(); BAR();
    __builtin_amdgcn_s_setprio(1);
    MM(0,0); MM(1,0); MM(2,0); MM(3,0);
    MM(0,1); MM(1,1); MM(2,1); MM(3,1);
    __builtin_amdgcn_s_setprio(0);
    BAR(); FENCE();

    LDB_(2); LDB_(3);
    if (more) STAGE_B(t + 2, stg);
    FENCE(); BAR();
    __builtin_amdgcn_s_setprio(1);
    MM(0,2); MM(1,2); MM(2,2); MM(3,2);
    MM(0,3); MM(1,3); MM(2,3); MM(3,3);
    __builtin_amdgcn_s_setprio(0);
    BAR(); FENCE();

    cur = (cur == 2) ? 0 : cur + 1;
  }

  #pragma unroll
  for (int m = 0; m < 4; ++m) {
    #pragma unroll
    for (int n = 0; n < 4; ++n) {
      #pragma unroll
      for (int j = 0; j < 4; ++j) {
        const int grow = bm + wr + m * 16 + ah * 4 + j;
        const int gcol = bn + wc + n * 16 + al;
        float v = acc[m][n][j] * scale;
        if (bias_mode == 1)      v += bias[z * sBiasZ + gcol];
        else if (bias_mode == 2) v += bias[z * sBiasZ + grow];
        const long idx = z * sCz + (long)grow * ldc + gcol;
        if (OUT_F32) ((float*)Cp)[idx] = v;
        else         ((unsigned short*)Cp)[idx] = bf16_rne(v);
      }
    }
  }
}

// ---------------------------------------------------------------------------
__device__ __forceinline__ void cvt8(const float* in, unsigned short* out, long i) {
  f32x4 a = *(const f32x4*)(in + i * 8);
  f32x4 b = *(const f32x4*)(in + i * 8 + 4);
  u32x4 w;
  w[0] = pack2(a[0], a[1]); w[1] = pack2(a[2], a[3]);
  w[2] = pack2(b[0], b[1]); w[3] = pack2(b[2], b[3]);
  *(u32x4*)(out + i * 8) = w;
}

__global__ __launch_bounds__(256) void mega_cvt2(
    const float* __restrict__ wq, const float* __restrict__ wk,
    const float* __restrict__ wv, const float* __restrict__ wo,
    const float* __restrict__ query, const float* __restrict__ key_,
    const float* __restrict__ bq, const float* __restrict__ bk,
    unsigned short* __restrict__ Wb, unsigned short* __restrict__ qf,
    unsigned short* __restrict__ kf, float* __restrict__ bqk)
{
  const int b = blockIdx.x;
  if (b < 2048) {
    const long i = (long)(b & 511) * 256 + threadIdx.x;
    if (b < 512)        cvt8(wq, Wb,            i);
    else if (b < 1024)  cvt8(wk, Wb + 1048576,  i);
    else if (b < 1536)  cvt8(wv, Wb + 2097152,  i);
    else                cvt8(wo, Wb + 3145728,  i);
  } else if (b < 6144) {
    cvt8(query, qf, (long)(b - 2048) * 256 + threadIdx.x);
  } else if (b < 10240) {
    cvt8(key_,  kf, (long)(b - 6144) * 256 + threadIdx.x);
  } else {
    const int t = (b - 10240) * 256 + threadIdx.x;
    if (t < 1024) bqk[t] = bq[t];
    else          bqk[t] = bk[t - 1024];
  }
}

__global__ __launch_bounds__(256) void cvt_f32_bf16(
    const float* __restrict__ in, unsigned short* __restrict__ out, int n8)
{
  const int i = blockIdx.x * 256 + threadIdx.x;
  if (i >= n8) return;
  cvt8(in, out, i);
}

// ---------------------------------------------------------------------------
__global__ __launch_bounds__(256) void softmax_inplace(unsigned short* __restrict__ P) {
  const long row = blockIdx.x;
  unsigned short* pr = P + row * 2048;
  const int tid = threadIdx.x;

  u32x4 raw = *(const u32x4*)&pr[tid * 8];
  float s[8];
  #pragma unroll
  for (int i = 0; i < 4; ++i) {
    unsigned int u = raw[i];
    s[2 * i]     = __builtin_bit_cast(float, u << 16);
    s[2 * i + 1] = __builtin_bit_cast(float, u & 0xFFFF0000u);
  }
  float m = s[0];
  #pragma unroll
  for (int i = 1; i < 8; ++i) m = fmaxf(m, s[i]);
  #pragma unroll
  for (int off = 32; off >= 1; off >>= 1) m = fmaxf(m, __shfl_xor(m, off));

  __shared__ float redm[4], reds[4];
  const int wid = tid >> 6, lane = tid & 63;
  if (lane == 0) redm[wid] = m;
  __syncthreads();
  m = fmaxf(fmaxf(redm[0], redm[1]), fmaxf(redm[2], redm[3]));

  float e[8], sum = 0.f;
  #pragma unroll
  for (int i = 0; i < 8; ++i) { e[i] = __expf(s[i] - m); sum += e[i]; }
  #pragma unroll
  for (int off = 32; off >= 1; off >>= 1) sum += __shfl_xor(sum, off);
  if (lane == 0) reds[wid] = sum;
  __syncthreads();
  sum = reds[0] + reds[1] + reds[2] + reds[3];
  const float inv = 1.0f / sum;

  u32x4 outw;
  #pragma unroll
  for (int i = 0; i < 4; ++i) outw[i] = pack2(e[2 * i] * inv, e[2 * i + 1] * inv);
  *(u32x4*)&pr[tid * 8] = outw;
}

// ---------------------------------------------------------------------------
extern "C" void kernel_launch(void* const* d_in, const int* in_sizes, int n_in,
                              void* d_out, int out_size, void* d_ws, size_t ws_size,
                              hipStream_t stream) {
  const float* query = (const float*)d_in[0];
  const float* key_  = (const float*)d_in[1];
  const float* value = (const float*)d_in[2];
  const float* Wq    = (const float*)d_in[3];
  const float* bq    = (const float*)d_in[4];
  const float* Wk    = (const float*)d_in[5];
  const float* bk    = (const float*)d_in[6];
  const float* Wv    = (const float*)d_in[7];
  const float* bv    = (const float*)d_in[8];
  const float* Wo    = (const float*)d_in[9];
  const float* bo    = (const float*)d_in[10];

  unsigned short* ws = (unsigned short*)d_ws;
  unsigned short* qf = ws;                        // [8192][1024] -> vf -> P lower
  unsigned short* kf = ws + 8388608;              // [8192][1024] -> P upper
  unsigned short* vf = ws;                        // overlays dead qf
  unsigned short* P  = ws;                        // [4][2048][2048]
  unsigned short* q  = ws + 16777216;             // [2][8.4M] q,k -> later o
  unsigned short* vT = ws + 33554432;             // [1024][8192]
  unsigned short* Wb = ws + 41943040;             // 4 x [1024][1024] bf16
  float*          bqk= (float*)(ws + 46137344);   // [2][1024] fp32
  unsigned short* o  = q;                         // overlays dead q

  const dim3 blk(256), blk8(512);

  // 0: all prologue conversions + bias copy in ONE dispatch
  mega_cvt2<<<dim3(10248), blk, 0, stream>>>(Wq, Wk, Wv, Wo, query, key_,
                                             bq, bk, Wb, qf, kf, bqk);

  // 1: [q;k] projections, z=2. M=8192, N=1024, K=1024. 256 blocks, 1 round.
  gemm256<0><<<dim3(4, 32, 2), blk8, 0, stream>>>(qf, Wb, q,
      1024, 1024, 1024, 1024, 8388608L, 1048576L, 8388608L, 1024L, 1.0f, bqk, 1);

  // 2: convert value (into region freed by qf)
  cvt_f32_bf16<<<dim3(4096), blk, 0, stream>>>(value, vf, 1048576);

  // 3: vT = Wv @ vf^T + bv. M=1024, N=8192, K=1024, bias per-row. 256 blocks.
  gemm8<0><<<dim3(64, 4, 1), blk8, 0, stream>>>(Wb + 2097152, vf, vT,
      1024, 1024, 1024, 8192, 0L, 0L, 0L, 0L, 1.0f, bv, 2);

  // 4: P = q @ k^T / 32, z=4. M=N=2048, K=1024. 256 blocks, 1 round.
  gemm256<0><<<dim3(8, 8, 4), blk8, 0, stream>>>(q, q + 8388608, P,
      1024, 1024, 1024, 2048, 2097152L, 2097152L, 4194304L, 0L, 0.03125f, nullptr, 0);

  // 5: softmax rows in place (8192 rows x 2048)
  softmax_inplace<<<dim3(8192), blk, 0, stream>>>(P);

  // 6: o = P @ vT^T, z=4. M=2048, N=1024, K=2048. 256 blocks.
  gemm8<0><<<dim3(8, 8, 4), blk8, 0, stream>>>(P, vT, o,
      2048, 2048, 8192, 1024, 4194304L, 2048L, 2097152L, 0L, 1.0f, nullptr, 0);

  // 7: out = o @ Wo^T + bo (fp32 out). M=8192, N=1024, K=1024. 256 blocks.
  gemm8<1><<<dim3(8, 32, 1), blk8, 0, stream>>>(o, Wb + 3145728, d_out,
      1024, 1024, 1024, 1024, 0L, 0L, 0L, 0L, 1.0f, bo, 1);
}